// Round 6
// baseline (13915.182 us; speedup 1.0000x reference)
//
#include <hip/hip_runtime.h>

// LSTM: S=512, B=64, IN=H=1024, 2 layers sharing weight_ih/weight_hh/bias.
// Persistent kernel, layers software-pipelined (layer0 step s, layer1 step s-1).
// Grid barrier: distributed per-block flag array (no RMW, no release fence).
// Round 6: move the h fan-out off the LLC onto per-XCD L2s.
//   Round-5 null (2x occupancy, same dur) proved the limiter is a shared
//   resource: ~786k coherent LLC requests/step (48MB of sc0sc1 A-reads that
//   bypass L1/L2) + 65k-request poll storms. Fix:
//   - A-loads are now PLAIN cached loads (L2/L1 allocate);
//   - each wave issues `buffer_inv sc0 sc1` once per step after the barrier
//     (LLVM's agent-acquire sequence; self-ordered vs this wave's later vmem)
//     so the parity-reused h lines can never be served stale from L1/L2;
//   - ALL global stores are sc0sc1 write-through (h, out, finals) so the inv
//     can never discard dirty lines;
//   - poll thinned: flags contiguous 4B; wave 0 polls 4 flags/lane via one
//     coherent dwordx4 + min + ballot (64 reqs/block/round, was 256).
//   First CU per XCD pulls each h line from LLC into L2; the other 31 hit L2.

typedef __attribute__((ext_vector_type(8))) short short8;
typedef __attribute__((ext_vector_type(4))) unsigned uint4v;
typedef __attribute__((ext_vector_type(16))) float f32x16;

#define NBLK 256

__device__ __forceinline__ short f2bf(float f) {
  unsigned u = __float_as_uint(f);
  u += 0x7FFFu + ((u >> 16) & 1u);   // RTNE
  return (short)(u >> 16);
}
__device__ __forceinline__ float fsig(float x) { return 1.0f / (1.0f + __expf(-x)); }
__device__ __forceinline__ float ftanh(float x) {
  float ax = fabsf(x);
  float e = __expf(-2.0f * ax);
  float t = (1.0f - e) / (1.0f + e);
  return x < 0.0f ? -t : t;
}

// ---------------- prep kernels ----------------

__global__ void cast_x(const float* __restrict__ x, short* __restrict__ xbf, int n8) {
  int i = blockIdx.x * blockDim.x + threadIdx.x;
  if (i >= n8) return;
  const float4* p = (const float4*)x + (size_t)i * 2;
  float4 a = p[0], b = p[1];
  short8 o;
  o[0] = f2bf(a.x); o[1] = f2bf(a.y); o[2] = f2bf(a.z); o[3] = f2bf(a.w);
  o[4] = f2bf(b.x); o[5] = f2bf(b.y); o[6] = f2bf(b.z); o[7] = f2bf(b.w);
  ((short8*)xbf)[i] = o;
}

// Pack W = [W_ih | W_hh] (4096 x 2048) into MFMA B-fragment order, bf16.
__global__ void pack_w(const float* __restrict__ wih, const float* __restrict__ whh,
                       short* __restrict__ wp) {
  int p = blockIdx.x * blockDim.x + threadIdx.x;   // < 128*128*64
  if (p >= 128 * 128 * 64) return;
  int hb = p >> 13;
  int rem = p & 8191;
  int k4 = rem >> 6;
  int lane = rem & 63;
  int colp = lane & 31;
  int sub = lane >> 5;
  int type = colp >> 3;
  int u = colp & 7;
  int jrow = type * 1024 + hb * 8 + u;
  int k0 = k4 * 16 + sub * 8;
  const float* src = (k0 < 1024) ? (wih + (size_t)jrow * 1024 + k0)
                                 : (whh + (size_t)jrow * 1024 + (k0 - 1024));
  short8 o;
#pragma unroll
  for (int j = 0; j < 8; ++j) o[j] = f2bf(src[j]);
  ((short8*)wp)[p] = o;
}

__global__ void pack_bias(const float* __restrict__ bih, const float* __restrict__ bhh,
                          float* __restrict__ bpk) {
  int i = blockIdx.x * blockDim.x + threadIdx.x;
  if (i >= 4096) return;
  int hb = i >> 5, colp = i & 31;
  int j = (colp >> 3) * 1024 + hb * 8 + (colp & 7);
  bpk[i] = bih[j] + bhh[j];
}

// ---------------- asm load pipeline (plain cached loads) ----------------

template<int OFF>
__device__ __forceinline__ short8 ldAasm(const short* p) {
  short8 d;
  asm volatile("global_load_dwordx4 %0, %1, off offset:%2"
               : "=&v"(d) : "v"(p), "n"(OFF));
  return d;
}

#define WAITV(n) do { asm volatile("s_waitcnt vmcnt(" #n ")" ::: "memory"); \
                      __builtin_amdgcn_sched_barrier(0); } while (0)
#define SB() __builtin_amdgcn_sched_barrier(0)
// Per-wave L1+L2 invalidate (agent-acquire style). Self-ordered vs this
// wave's subsequent vmem ops; issued AFTER the barrier syncthreads (all
// waves' vmcnt already drained at barrier entry).
#define INVL2() asm volatile("buffer_inv sc0 sc1" ::: "memory")

// Issue one group: 4 K-slices x 2 row-halves = 8 loads.
template<int G>
__device__ __forceinline__ void issue_group(const short* ar0, const short* ar1,
                                            short8 (&b0)[4], short8 (&b1)[4]) {
#define ISSUE2(j) \
  b0[j] = ldAasm<(G * 4 + (j)) * 32>(ar0); \
  b1[j] = ldAasm<(G * 4 + (j)) * 32>(ar1);
  ISSUE2(0) ISSUE2(1) ISSUE2(2) ISSUE2(3)
#undef ISSUE2
}

template<int G>
__device__ __forceinline__ void mfma_group(const short8 (&b0)[4], const short8 (&b1)[4],
                                           const short8 (&w)[16], f32x16& acc0, f32x16& acc1) {
#pragma unroll
  for (int j = 0; j < 4; ++j) {
    acc0 = __builtin_amdgcn_mfma_f32_32x32x16_bf16(b0[j], w[G * 4 + j], acc0, 0, 0, 0);
    acc1 = __builtin_amdgcn_mfma_f32_32x32x16_bf16(b1[j], w[G * 4 + j], acc1, 0, 0, 0);
  }
}

// 16 K-slices/wave, weights preloaded in registers, 4 groups, depth-2 pipeline.
// Max 16 VMEM outstanding. No other VMEM between the asm loads and the waits.
__device__ __forceinline__ void gemm16p(const short* ar0, const short* ar1,
                                        const short8 (&w)[16], f32x16& acc0, f32x16& acc1) {
  short8 p0[4], p1[4], q0[4], q1[4];
  issue_group<0>(ar0, ar1, p0, p1);           //  8 in flight
  issue_group<1>(ar0, ar1, q0, q1);           // 16 in flight
  WAITV(8);  mfma_group<0>(p0, p1, w, acc0, acc1); SB();
  issue_group<2>(ar0, ar1, p0, p1);           // 16 in flight
  WAITV(8);  mfma_group<1>(q0, q1, w, acc0, acc1); SB();
  issue_group<3>(ar0, ar1, q0, q1);
  WAITV(8);  mfma_group<2>(p0, p1, w, acc0, acc1); SB();
  WAITV(0);  mfma_group<3>(q0, q1, w, acc0, acc1);
}

// ---------------- persistent LSTM kernel ----------------
// 256 blocks x 512 threads (1 block/CU, 8 waves = 2/SIMD).
// Block = (layer = bid>>7, hb = bid&127). 64 rows x 32 cols (8 units x 4 gates),
// K=2048 split across 8 waves (256 K-elems = 16 slices each).
__global__ __launch_bounds__(512, 2)
void lstm_loop(const short* __restrict__ xbf, const short* __restrict__ wp,
               const float* __restrict__ bpk, short* __restrict__ h0buf,
               short* __restrict__ h1buf, float* __restrict__ out,
               unsigned* __restrict__ flags)
{
  const int bid = blockIdx.x;
  const int layer = bid >> 7;
  const int hb = bid & 127;
  const int tid = threadIdx.x;
  const int lane = tid & 63;
  const int wv = tid >> 6;        // 0..7 = K-eighth
  const int col = lane & 31;
  const int sub = lane >> 5;

  __shared__ float red[4][64 * 37];   // partial gate sums (pad 37), 37,888 B

  const short8* wgl = (const short8*)(wp + (size_t)hb * 65536) + (size_t)(wv * 16) * 64 + lane;

  // Preload this wave's weight slice into registers: 16 x short8 = 64 regs,
  // live across all 513 steps.
  short8 wreg[16];
#pragma unroll
  for (int i = 0; i < 16; ++i) wreg[i] = wgl[i * 64];

  // epilogue assignment (threads 0-255): thread -> (row = tid>>2, unit pair = tid&3)
  const int r = tid >> 2;
  const int p2 = tid & 3;
  const int u0 = p2 * 2, u1 = u0 + 1;
  float bi0 = 0, bi1 = 0, bf0 = 0, bf1 = 0, bg0 = 0, bg1 = 0, bo0 = 0, bo1 = 0;
  if (tid < 256) {
    bi0 = bpk[hb * 32 + u0];      bi1 = bpk[hb * 32 + u1];
    bf0 = bpk[hb * 32 + 8 + u0];  bf1 = bpk[hb * 32 + 8 + u1];
    bg0 = bpk[hb * 32 + 16 + u0]; bg1 = bpk[hb * 32 + 16 + u1];
    bo0 = bpk[hb * 32 + 24 + u0]; bo1 = bpk[hb * 32 + 24 + u1];
  }
  const int hg = hb * 8 + u0;     // global unit index (even)
  float c0v = 0.0f, c1v = 0.0f;   // cell state in registers (threads 0-255)

  // wave wv: operand = (wv<4 ? A0 : A1), K range (wv&3)*256 .. +256
  const int kbase = (wv & 3) * 256;

  for (int s = 0; s < 513; ++s) {
    // per-wave cache invalidate: h parity lines read below must not be served
    // from stale L1/L2 (addresses reused every 2 steps). Self-ordered vs this
    // wave's following loads. No dirty lines exist (all stores write-through).
    INVL2();

    const bool active = (layer == 0) ? (s < 512) : (s >= 1);   // uniform in block
    const int t = (layer == 0) ? s : (s - 1);
    if (active) {
      const short* A0 = (layer == 0) ? (xbf + (size_t)t * 65536)
                                     : (h0buf + (size_t)(t & 1) * 65536);
      const short* A1 = (layer == 0) ? (h0buf + (size_t)((t + 1) & 1) * 65536)
                                     : (h1buf + (size_t)((t + 1) & 1) * 65536);
      const short* Ah = (wv < 4) ? A0 : A1;
      const short* ar0 = Ah + (size_t)col * 1024 + kbase + sub * 8;
      const short* ar1 = ar0 + 32 * 1024;

      f32x16 acc0, acc1;
#pragma unroll
      for (int rr = 0; rr < 16; ++rr) { acc0[rr] = 0.0f; acc1[rr] = 0.0f; }

      gemm16p(ar0, ar1, wreg, acc0, acc1);

      // two-phase cross-wave K reduction into 4 areas
      // (C layout: col=lane&31, row=(rr&3)+8*(rr>>2)+4*sub)
      if (wv < 4) {
#pragma unroll
        for (int rr = 0; rr < 16; ++rr) {
          int q = (rr & 3) + 8 * (rr >> 2) + 4 * sub;
          red[wv][q * 37 + col] = acc0[rr];
          red[wv][(q + 32) * 37 + col] = acc1[rr];
        }
      }
      __syncthreads();
      if (wv >= 4) {
#pragma unroll
        for (int rr = 0; rr < 16; ++rr) {
          int q = (rr & 3) + 8 * (rr >> 2) + 4 * sub;
          red[wv - 4][q * 37 + col] += acc0[rr];
          red[wv - 4][(q + 32) * 37 + col] += acc1[rr];
        }
      }
      __syncthreads();

      // LSTM cell update on threads 0-255: row r, units u0,u1; sum 4 partials
      if (tid < 256) {
        const int b0 = r * 37;
        auto rsum = [&](int off) {
          return red[0][b0 + off] + red[1][b0 + off] + red[2][b0 + off] + red[3][b0 + off];
        };
        float pi0 = rsum(u0) + bi0;
        float pf0 = rsum(8 + u0) + bf0;
        float pg0 = rsum(16 + u0) + bg0;
        float po0 = rsum(24 + u0) + bo0;
        float ig0 = fsig(pi0), fg0 = fsig(pf0), gg0 = ftanh(pg0), og0 = fsig(po0);
        c0v = fg0 * c0v + ig0 * gg0;
        float h0v = og0 * ftanh(c0v);

        float pi1 = rsum(u1) + bi1;
        float pf1 = rsum(8 + u1) + bf1;
        float pg1 = rsum(16 + u1) + bg1;
        float po1 = rsum(24 + u1) + bo1;
        float ig1 = fsig(pi1), fg1 = fsig(pf1), gg1 = ftanh(pg1), og1 = fsig(po1);
        c1v = fg1 * c1v + ig1 * gg1;
        float h1v = og1 * ftanh(c1v);

        // coherent packed h store (2 bf16 per uint), write-through (no dirty L2)
        unsigned hp = (unsigned)(unsigned short)f2bf(h0v)
                    | ((unsigned)(unsigned short)f2bf(h1v) << 16);
        unsigned* hw = (unsigned*)(((layer == 0) ? h0buf : h1buf) + (size_t)(t & 1) * 65536)
                     + ((r * 1024 + hg) >> 1);
        __hip_atomic_store(hw, hp, __ATOMIC_RELAXED, __HIP_MEMORY_SCOPE_AGENT);

        // out/final stores also write-through (inv must never see dirty lines)
        union { float2 f; unsigned long long u; } cv;
        if (layer == 1) {
          cv.f = make_float2(h0v, h1v);
          __hip_atomic_store((unsigned long long*)(out + (size_t)t * 65536 + r * 1024 + hg),
                             cv.u, __ATOMIC_RELAXED, __HIP_MEMORY_SCOPE_AGENT);
        }
        if (t == 511) {
          const size_t HN = 33554432;         // outputs elements
          const size_t CN = HN + 131072;      // + h_n elements
          cv.f = make_float2(h0v, h1v);
          __hip_atomic_store((unsigned long long*)(out + HN + (size_t)layer * 65536 + r * 1024 + hg),
                             cv.u, __ATOMIC_RELAXED, __HIP_MEMORY_SCOPE_AGENT);
          cv.f = make_float2(c0v, c1v);
          __hip_atomic_store((unsigned long long*)(out + CN + (size_t)layer * 65536 + r * 1024 + hg),
                             cv.u, __ATOMIC_RELAXED, __HIP_MEMORY_SCOPE_AGENT);
        }
      }
    }

    // ---- grid barrier: distributed flag array (no RMW, no release fence) ----
    __syncthreads();   // each wave drains its vmcnt: h stores at LLC before signal
    if (tid == 0) {
      asm volatile("s_waitcnt vmcnt(0)" ::: "memory");
      __hip_atomic_store(flags + bid, (unsigned)(s + 1),
                         __ATOMIC_RELAXED, __HIP_MEMORY_SCOPE_AGENT);
    }
    if (wv == 0) {
      // wave 0 polls all 256 flags: 4 flags/lane via one coherent dwordx4
      const unsigned tgt = (unsigned)(s + 1);
      const unsigned* fp = flags + lane * 4;
      while (true) {
        uint4v f;
        asm volatile("global_load_dwordx4 %0, %1, off sc0 sc1\n\t"
                     "s_waitcnt vmcnt(0)"
                     : "=&v"(f) : "v"(fp) : "memory");
        unsigned mn = min(min(f[0], f[1]), min(f[2], f[3]));
        if (__ballot(mn < tgt) == 0ull) break;
        __builtin_amdgcn_s_sleep(1);
      }
    }
    __syncthreads();   // wave 0's verdict releases all waves
    // freshness of next step's h reads is provided by the per-wave INVL2()
  }
}

// ---------------- launch ----------------
extern "C" void kernel_launch(void* const* d_in, const int* in_sizes, int n_in,
                              void* d_out, int out_size, void* d_ws, size_t ws_size,
                              hipStream_t stream) {
  const float* x = (const float*)d_in[0];
  const float* wih = (const float*)d_in[1];
  const float* whh = (const float*)d_in[2];
  const float* bih = (const float*)d_in[3];
  const float* bhh = (const float*)d_in[4];
  float* outf = (float*)d_out;
  char* ws = (char*)d_ws;

  short* xbf = (short*)(ws);                       // 67,108,864 B
  short* wp = (short*)(ws + 67108864);             // 33,554,432 B
  float* bpk = (float*)(ws + 100663296);           // 16,384 B
  short* h0buf = (short*)(ws + 100679680);         // 262,144 B (2 parities)
  short* h1buf = (short*)(ws + 100941824);         // 262,144 B
  unsigned* flags = (unsigned*)(ws + 101203968);   // 256 x 4 B contiguous

  hipMemsetAsync(h0buf, 0, 524288 + 16384, stream);

  cast_x<<<16384, 256, 0, stream>>>(x, xbf, 4194304);
  pack_w<<<4096, 256, 0, stream>>>(wih, whh, wp);
  pack_bias<<<16, 256, 0, stream>>>(bih, bhh, bpk);

  lstm_loop<<<dim3(NBLK), dim3(512), 0, stream>>>(xbf, wp, bpk, h0buf, h1buf, outf, flags);
}

// Round 7
// 4318.988 us; speedup vs baseline: 3.2219x; 3.2219x over previous
//
#include <hip/hip_runtime.h>

// LSTM: S=512, B=64, IN=H=1024, 2 layers sharing weight_ih/weight_hh/bias.
// Persistent kernel, layers software-pipelined (layer0 step s, layer1 step s-1).
// Cross-block h exchange: AGENT-scope coherent accesses (sc0 sc1 -> LLC).
// Grid barrier: distributed per-block flag array (no RMW, no release fence).
// Round 7: FRAGMENT-ORDER ACTIVATIONS. Round-5 showed the limiter is shared
// (occupancy-doubling null); round-6's buffer_inv was a disaster (global inv
// storm). New attack: A-panel reads were 64 lanes x 16B at 2KB stride = 32
// LLC requests/instr with 32B/line used (~2.1M coherent requests/step).
// Store x AND h in MFMA-fragment order [slice][lane(sub,col)][8elems]:
//   - wave loads become 1024B contiguous (8 full-line requests, 4x fewer)
//   - epilogue h-stores become 16B-contiguous per row (coalesced, was 4B
//     scatter at 2KB stride)
//   - per-group base pointers (slice stride 1024B > 13-bit asm offset)
// Everything else = round 5 (proven): counted-vmcnt pipeline, 8 waves,
// two-phase LDS reduce, thinned wave-0 dwordx4 poll from round 6.

typedef __attribute__((ext_vector_type(8))) short short8;
typedef __attribute__((ext_vector_type(4))) unsigned uint4v;
typedef __attribute__((ext_vector_type(16))) float f32x16;

#define NBLK 256

__device__ __forceinline__ short f2bf(float f) {
  unsigned u = __float_as_uint(f);
  u += 0x7FFFu + ((u >> 16) & 1u);   // RTNE
  return (short)(u >> 16);
}
__device__ __forceinline__ float fsig(float x) { return 1.0f / (1.0f + __expf(-x)); }
__device__ __forceinline__ float ftanh(float x) {
  float ax = fabsf(x);
  float e = __expf(-2.0f * ax);
  float t = (1.0f - e) / (1.0f + e);
  return x < 0.0f ? -t : t;
}

// ---------------- prep kernels ----------------

// Pack x into fragment order: per t, region(row>=32) of 32768 shorts,
// dest group = (slice*64 + sub*32 + (row&31))*8, holding x[row][slice*16+sub*8 ..+8].
__global__ void cast_x(const float* __restrict__ x, short* __restrict__ xbf, int n8) {
  int i = blockIdx.x * blockDim.x + threadIdx.x;
  if (i >= n8) return;
  int t = i >> 13;
  int rem = i & 8191;
  int region = rem >> 12;
  int srem = rem & 4095;
  int slice = srem >> 6;
  int lane = srem & 63;
  int sub = lane >> 5;
  int row = region * 32 + (lane & 31);
  int k0 = slice * 16 + sub * 8;
  const float* src = x + (size_t)t * 65536 + row * 1024 + k0;
  const float4* p = (const float4*)src;
  float4 a = p[0], b = p[1];
  short8 o;
  o[0] = f2bf(a.x); o[1] = f2bf(a.y); o[2] = f2bf(a.z); o[3] = f2bf(a.w);
  o[4] = f2bf(b.x); o[5] = f2bf(b.y); o[6] = f2bf(b.z); o[7] = f2bf(b.w);
  ((short8*)xbf)[i] = o;
}

// Pack W = [W_ih | W_hh] (4096 x 2048) into MFMA B-fragment order, bf16.
__global__ void pack_w(const float* __restrict__ wih, const float* __restrict__ whh,
                       short* __restrict__ wp) {
  int p = blockIdx.x * blockDim.x + threadIdx.x;   // < 128*128*64
  if (p >= 128 * 128 * 64) return;
  int hb = p >> 13;
  int rem = p & 8191;
  int k4 = rem >> 6;
  int lane = rem & 63;
  int colp = lane & 31;
  int sub = lane >> 5;
  int type = colp >> 3;
  int u = colp & 7;
  int jrow = type * 1024 + hb * 8 + u;
  int k0 = k4 * 16 + sub * 8;
  const float* src = (k0 < 1024) ? (wih + (size_t)jrow * 1024 + k0)
                                 : (whh + (size_t)jrow * 1024 + (k0 - 1024));
  short8 o;
#pragma unroll
  for (int j = 0; j < 8; ++j) o[j] = f2bf(src[j]);
  ((short8*)wp)[p] = o;
}

__global__ void pack_bias(const float* __restrict__ bih, const float* __restrict__ bhh,
                          float* __restrict__ bpk) {
  int i = blockIdx.x * blockDim.x + threadIdx.x;
  if (i >= 4096) return;
  int hb = i >> 5, colp = i & 31;
  int j = (colp >> 3) * 1024 + hb * 8 + (colp & 7);
  bpk[i] = bih[j] + bhh[j];
}

// ---------------- asm load pipeline ----------------

template<bool COH, int OFF>
__device__ __forceinline__ short8 ldAasm(const short* p) {
  short8 d;
  if constexpr (COH)
    asm volatile("global_load_dwordx4 %0, %1, off offset:%2 sc0 sc1"
                 : "=&v"(d) : "v"(p), "n"(OFF));
  else
    asm volatile("global_load_dwordx4 %0, %1, off offset:%2"
                 : "=&v"(d) : "v"(p), "n"(OFF));
  return d;
}

#define WAITV(n) do { asm volatile("s_waitcnt vmcnt(" #n ")" ::: "memory"); \
                      __builtin_amdgcn_sched_barrier(0); } while (0)
#define SB() __builtin_amdgcn_sched_barrier(0)

// Issue one group: 4 slices x 2 row-halves = 8 loads. Slice stride = 1024B
// (fragment order, contiguous per wave); group base = ar + G*2048 shorts.
template<bool COH, int G>
__device__ __forceinline__ void issue_group(const short* ar0, const short* ar1,
                                            short8 (&b0)[4], short8 (&b1)[4]) {
  const short* g0 = ar0 + G * 2048;
  const short* g1 = ar1 + G * 2048;
  b0[0] = ldAasm<COH, 0>(g0);    b1[0] = ldAasm<COH, 0>(g1);
  b0[1] = ldAasm<COH, 1024>(g0); b1[1] = ldAasm<COH, 1024>(g1);
  b0[2] = ldAasm<COH, 2048>(g0); b1[2] = ldAasm<COH, 2048>(g1);
  b0[3] = ldAasm<COH, 3072>(g0); b1[3] = ldAasm<COH, 3072>(g1);
}

template<int G>
__device__ __forceinline__ void mfma_group(const short8 (&b0)[4], const short8 (&b1)[4],
                                           const short8 (&w)[16], f32x16& acc0, f32x16& acc1) {
#pragma unroll
  for (int j = 0; j < 4; ++j) {
    acc0 = __builtin_amdgcn_mfma_f32_32x32x16_bf16(b0[j], w[G * 4 + j], acc0, 0, 0, 0);
    acc1 = __builtin_amdgcn_mfma_f32_32x32x16_bf16(b1[j], w[G * 4 + j], acc1, 0, 0, 0);
  }
}

// 16 K-slices/wave, weights preloaded in registers, 4 groups, depth-2 pipeline.
// Max 16 VMEM outstanding. No other VMEM between the asm loads and the waits.
template<bool COH>
__device__ __forceinline__ void gemm16p(const short* ar0, const short* ar1,
                                        const short8 (&w)[16], f32x16& acc0, f32x16& acc1) {
  short8 p0[4], p1[4], q0[4], q1[4];
  issue_group<COH, 0>(ar0, ar1, p0, p1);           //  8 in flight
  issue_group<COH, 1>(ar0, ar1, q0, q1);           // 16 in flight
  WAITV(8);  mfma_group<0>(p0, p1, w, acc0, acc1); SB();
  issue_group<COH, 2>(ar0, ar1, p0, p1);           // 16 in flight
  WAITV(8);  mfma_group<1>(q0, q1, w, acc0, acc1); SB();
  issue_group<COH, 3>(ar0, ar1, q0, q1);
  WAITV(8);  mfma_group<2>(p0, p1, w, acc0, acc1); SB();
  WAITV(0);  mfma_group<3>(q0, q1, w, acc0, acc1);
}

// ---------------- persistent LSTM kernel ----------------
// 256 blocks x 512 threads (1 block/CU, 8 waves = 2/SIMD).
// Block = (layer = bid>>7, hb = bid&127). 64 rows x 32 cols (8 units x 4 gates),
// K=2048 split across 8 waves (256 K-elems = 16 slices each).
// Activation buffers (x per t, h per parity): two 32768-short regions
// (rows 0-31, rows 32-63), each region [64 slices][64 lanes][8 shorts].
__global__ __launch_bounds__(512, 2)
void lstm_loop(const short* __restrict__ xbf, const short* __restrict__ wp,
               const float* __restrict__ bpk, short* __restrict__ h0buf,
               short* __restrict__ h1buf, float* __restrict__ out,
               unsigned* __restrict__ flags)
{
  const int bid = blockIdx.x;
  const int layer = bid >> 7;
  const int hb = bid & 127;
  const int tid = threadIdx.x;
  const int lane = tid & 63;
  const int wv = tid >> 6;        // 0..7: wv<4 -> A0 operand, wv>=4 -> A1
  const int col = lane & 31;
  const int sub = lane >> 5;
  (void)col; (void)sub;

  __shared__ float red[4][64 * 37];   // partial gate sums (pad 37), 37,888 B

  const short8* wgl = (const short8*)(wp + (size_t)hb * 65536) + (size_t)(wv * 16) * 64 + lane;

  // Preload this wave's weight slice into registers: 16 x short8 = 64 regs,
  // live across all 513 steps.
  short8 wreg[16];
#pragma unroll
  for (int i = 0; i < 16; ++i) wreg[i] = wgl[i * 64];

  // epilogue assignment (threads 0-255): thread -> (row = tid>>2, unit pair = tid&3)
  const int r = tid >> 2;
  const int p2 = tid & 3;
  const int u0 = p2 * 2, u1 = u0 + 1;
  float bi0 = 0, bi1 = 0, bf0 = 0, bf1 = 0, bg0 = 0, bg1 = 0, bo0 = 0, bo1 = 0;
  if (tid < 256) {
    bi0 = bpk[hb * 32 + u0];      bi1 = bpk[hb * 32 + u1];
    bf0 = bpk[hb * 32 + 8 + u0];  bf1 = bpk[hb * 32 + 8 + u1];
    bg0 = bpk[hb * 32 + 16 + u0]; bg1 = bpk[hb * 32 + 16 + u1];
    bo0 = bpk[hb * 32 + 24 + u0]; bo1 = bpk[hb * 32 + 24 + u1];
  }
  const int hg = hb * 8 + u0;     // global unit index (even)
  float c0v = 0.0f, c1v = 0.0f;   // cell state in registers (threads 0-255)

  // fragment-order h store offset (shorts) within a parity buffer:
  // unit k=hg: slice=hb>>1, sub=hb&1, e=p2*2; lane=sub*32+(r&31); region=r>>5
  const int hoff = (r >> 5) * 32768
                 + (((hb >> 1) * 64 + (hb & 1) * 32 + (r & 31)) << 3) + p2 * 2;

  // A-operand base offset for this wave: slices (wv&3)*16.., lane-linear
  const int aoff = (wv & 3) * 8192 + lane * 8;
  const bool coh = !(layer == 0 && wv < 4);   // x plain cached; h coherent

  for (int s = 0; s < 513; ++s) {
    const bool active = (layer == 0) ? (s < 512) : (s >= 1);   // uniform in block
    const int t = (layer == 0) ? s : (s - 1);
    if (active) {
      const short* A0 = (layer == 0) ? (xbf + (size_t)t * 65536)
                                     : (h0buf + (size_t)(t & 1) * 65536);
      const short* A1 = (layer == 0) ? (h0buf + (size_t)((t + 1) & 1) * 65536)
                                     : (h1buf + (size_t)((t + 1) & 1) * 65536);
      const short* Ah = (wv < 4) ? A0 : A1;
      const short* ar0 = Ah + aoff;            // region rows 0-31
      const short* ar1 = ar0 + 32768;          // region rows 32-63

      f32x16 acc0, acc1;
#pragma unroll
      for (int rr = 0; rr < 16; ++rr) { acc0[rr] = 0.0f; acc1[rr] = 0.0f; }

      if (coh) gemm16p<true>(ar0, ar1, wreg, acc0, acc1);
      else     gemm16p<false>(ar0, ar1, wreg, acc0, acc1);

      // two-phase cross-wave K reduction into 4 areas
      // (C layout: col=lane&31, row=(rr&3)+8*(rr>>2)+4*sub)
      if (wv < 4) {
#pragma unroll
        for (int rr = 0; rr < 16; ++rr) {
          int q = (rr & 3) + 8 * (rr >> 2) + 4 * (lane >> 5);
          red[wv][q * 37 + (lane & 31)] = acc0[rr];
          red[wv][(q + 32) * 37 + (lane & 31)] = acc1[rr];
        }
      }
      __syncthreads();
      if (wv >= 4) {
#pragma unroll
        for (int rr = 0; rr < 16; ++rr) {
          int q = (rr & 3) + 8 * (rr >> 2) + 4 * (lane >> 5);
          red[wv - 4][q * 37 + (lane & 31)] += acc0[rr];
          red[wv - 4][(q + 32) * 37 + (lane & 31)] += acc1[rr];
        }
      }
      __syncthreads();

      // LSTM cell update on threads 0-255: row r, units u0,u1; sum 4 partials
      if (tid < 256) {
        const int b0 = r * 37;
        auto rsum = [&](int off) {
          return red[0][b0 + off] + red[1][b0 + off] + red[2][b0 + off] + red[3][b0 + off];
        };
        float pi0 = rsum(u0) + bi0;
        float pf0 = rsum(8 + u0) + bf0;
        float pg0 = rsum(16 + u0) + bg0;
        float po0 = rsum(24 + u0) + bo0;
        float ig0 = fsig(pi0), fg0 = fsig(pf0), gg0 = ftanh(pg0), og0 = fsig(po0);
        c0v = fg0 * c0v + ig0 * gg0;
        float h0v = og0 * ftanh(c0v);

        float pi1 = rsum(u1) + bi1;
        float pf1 = rsum(8 + u1) + bf1;
        float pg1 = rsum(16 + u1) + bg1;
        float po1 = rsum(24 + u1) + bo1;
        float ig1 = fsig(pi1), fg1 = fsig(pf1), gg1 = ftanh(pg1), og1 = fsig(po1);
        c1v = fg1 * c1v + ig1 * gg1;
        float h1v = og1 * ftanh(c1v);

        // coherent packed h store (2 bf16 per uint), fragment order, coalesced
        unsigned hp = (unsigned)(unsigned short)f2bf(h0v)
                    | ((unsigned)(unsigned short)f2bf(h1v) << 16);
        unsigned* hw = (unsigned*)(((layer == 0) ? h0buf : h1buf)
                                   + (size_t)(t & 1) * 65536 + hoff);
        __hip_atomic_store(hw, hp, __ATOMIC_RELAXED, __HIP_MEMORY_SCOPE_AGENT);

        if (layer == 1) {
          float2 o2 = make_float2(h0v, h1v);
          *(float2*)(out + (size_t)t * 65536 + r * 1024 + hg) = o2;
        }
        if (t == 511) {
          const size_t HN = 33554432;         // outputs elements
          const size_t CN = HN + 131072;      // + h_n elements
          *(float2*)(out + HN + (size_t)layer * 65536 + r * 1024 + hg) = make_float2(h0v, h1v);
          *(float2*)(out + CN + (size_t)layer * 65536 + r * 1024 + hg) = make_float2(c0v, c1v);
        }
      }
    }

    // ---- grid barrier: distributed flag array (no RMW, no release fence) ----
    __syncthreads();   // each wave drains its vmcnt: h stores at LLC before signal
    if (tid == 0) {
      asm volatile("s_waitcnt vmcnt(0)" ::: "memory");
      __hip_atomic_store(flags + bid, (unsigned)(s + 1),
                         __ATOMIC_RELAXED, __HIP_MEMORY_SCOPE_AGENT);
    }
    if (wv == 0) {
      // wave 0 polls all 256 flags: 4 flags/lane via one coherent dwordx4
      const unsigned tgt = (unsigned)(s + 1);
      const unsigned* fp = flags + lane * 4;
      while (true) {
        uint4v f;
        asm volatile("global_load_dwordx4 %0, %1, off sc0 sc1\n\t"
                     "s_waitcnt vmcnt(0)"
                     : "=&v"(f) : "v"(fp) : "memory");
        unsigned mn = min(min(f[0], f[1]), min(f[2], f[3]));
        if (__ballot(mn < tgt) == 0ull) break;
        __builtin_amdgcn_s_sleep(1);
      }
    }
    __syncthreads();   // wave 0's verdict releases all waves
    // no acquire fence: subsequent cross-block reads are sc0sc1 coherent loads
  }
}

// ---------------- launch ----------------
extern "C" void kernel_launch(void* const* d_in, const int* in_sizes, int n_in,
                              void* d_out, int out_size, void* d_ws, size_t ws_size,
                              hipStream_t stream) {
  const float* x = (const float*)d_in[0];
  const float* wih = (const float*)d_in[1];
  const float* whh = (const float*)d_in[2];
  const float* bih = (const float*)d_in[3];
  const float* bhh = (const float*)d_in[4];
  float* outf = (float*)d_out;
  char* ws = (char*)d_ws;

  short* xbf = (short*)(ws);                       // 67,108,864 B
  short* wp = (short*)(ws + 67108864);             // 33,554,432 B
  float* bpk = (float*)(ws + 100663296);           // 16,384 B
  short* h0buf = (short*)(ws + 100679680);         // 262,144 B (2 parities)
  short* h1buf = (short*)(ws + 100941824);         // 262,144 B
  unsigned* flags = (unsigned*)(ws + 101203968);   // 256 x 4 B contiguous

  hipMemsetAsync(h0buf, 0, 524288 + 16384, stream);

  cast_x<<<16384, 256, 0, stream>>>(x, xbf, 4194304);
  pack_w<<<4096, 256, 0, stream>>>(wih, whh, wp);
  pack_bias<<<16, 256, 0, stream>>>(bih, bhh, bpk);

  lstm_loop<<<dim3(NBLK), dim3(512), 0, stream>>>(xbf, wp, bpk, h0buf, h1buf, outf, flags);
}